// Round 1
// baseline (128.560 us; speedup 1.0000x reference)
//
#include <hip/hip_runtime.h>

typedef __attribute__((ext_vector_type(4))) float f32x4;
typedef __attribute__((ext_vector_type(8))) short short8;

#define S_LEN 4096
#define DM    1024
#define NH    16
#define DH    64
#define WIN   256

__device__ inline unsigned short f2b(float f) {
  unsigned int x = __float_as_uint(f);
  unsigned int r = (x + 0x7fffu + ((x >> 16) & 1u)) >> 16;
  return (unsigned short)r;
}

// ---------------------------------------------------------------------------
// QKV projection: X[4096][1024] f32  x  W[1024][1024] f32 (row d, col e; used
// as B^T)  -> bf16 out [4096][1024].  128x128 tile, BK=32, 4 waves, 4x4 frags.
// blockIdx.z selects q/k/v.
// ---------------------------------------------------------------------------
__global__ __launch_bounds__(256) void gemm_qkv(
    const float* __restrict__ X,
    const float* __restrict__ Wq, const float* __restrict__ Wk, const float* __restrict__ Wv,
    const float* __restrict__ Bq, const float* __restrict__ Bk, const float* __restrict__ Bv,
    unsigned short* __restrict__ Qo, unsigned short* __restrict__ Ko, unsigned short* __restrict__ Vo)
{
  const int K = 1024, N = 1024;
  const float* W; const float* Bi; unsigned short* O;
  if (blockIdx.z == 0)      { W = Wq; Bi = Bq; O = Qo; }
  else if (blockIdx.z == 1) { W = Wk; Bi = Bk; O = Ko; }
  else                      { W = Wv; Bi = Bv; O = Vo; }

  __shared__ __align__(16) short sA[128 * 32];
  __shared__ __align__(16) short sB[128 * 32];

  const int t = threadIdx.x;
  const int lane = t & 63, wv = t >> 6;
  const int wm = wv >> 1, wn = wv & 1;
  const int lr = lane & 15, lg = lane >> 4;
  const int m0 = blockIdx.x * 128, n0 = blockIdx.y * 128;

  const int srow = t >> 2;          // staging row (i adds 64)
  const int scol = (t & 3) * 8;     // staging col (8 elems)

  f32x4 acc[4][4];
#pragma unroll
  for (int m = 0; m < 4; ++m)
#pragma unroll
    for (int n = 0; n < 4; ++n) acc[m][n] = (f32x4){0.f, 0.f, 0.f, 0.f};

  for (int e0 = 0; e0 < K; e0 += 32) {
    __syncthreads();
#pragma unroll
    for (int i = 0; i < 2; ++i) {
      const int row = i * 64 + srow;
      const float* ga = X + (size_t)(m0 + row) * K + e0 + scol;
      float4 a0 = *(const float4*)ga;
      float4 a1 = *(const float4*)(ga + 4);
      short8 av;
      av[0] = f2b(a0.x); av[1] = f2b(a0.y); av[2] = f2b(a0.z); av[3] = f2b(a0.w);
      av[4] = f2b(a1.x); av[5] = f2b(a1.y); av[6] = f2b(a1.z); av[7] = f2b(a1.w);
      *(short8*)(sA + row * 32 + scol) = av;

      const float* gb = W + (size_t)(n0 + row) * K + e0 + scol;
      float4 b0 = *(const float4*)gb;
      float4 b1 = *(const float4*)(gb + 4);
      short8 bv;
      bv[0] = f2b(b0.x); bv[1] = f2b(b0.y); bv[2] = f2b(b0.z); bv[3] = f2b(b0.w);
      bv[4] = f2b(b1.x); bv[5] = f2b(b1.y); bv[6] = f2b(b1.z); bv[7] = f2b(b1.w);
      *(short8*)(sB + row * 32 + scol) = bv;
    }
    __syncthreads();

    short8 af[4], bf[4];
#pragma unroll
    for (int m = 0; m < 4; ++m)
      af[m] = *(const short8*)(sA + (wm * 64 + m * 16 + lr) * 32 + lg * 8);
#pragma unroll
    for (int n = 0; n < 4; ++n)
      bf[n] = *(const short8*)(sB + (wn * 64 + n * 16 + lr) * 32 + lg * 8);
#pragma unroll
    for (int m = 0; m < 4; ++m)
#pragma unroll
      for (int n = 0; n < 4; ++n)
        acc[m][n] = __builtin_amdgcn_mfma_f32_16x16x32_bf16(af[m], bf[n], acc[m][n], 0, 0, 0);
  }

#pragma unroll
  for (int n = 0; n < 4; ++n) {
    const int gc = n0 + wn * 64 + n * 16 + lr;
    const float bias = Bi[gc];
#pragma unroll
    for (int m = 0; m < 4; ++m) {
      const int gr0 = m0 + wm * 64 + m * 16 + lg * 4;
#pragma unroll
      for (int r = 0; r < 4; ++r)
        O[(size_t)(gr0 + r) * N + gc] = f2b(acc[m][n][r] + bias);
    }
  }
}

// ---------------------------------------------------------------------------
// Output projection: A[4096][1024] bf16 x o_w[1024][1024] f32 (B^T) -> f32 out
// ---------------------------------------------------------------------------
__global__ __launch_bounds__(256) void gemm_out(
    const unsigned short* __restrict__ A,
    const float* __restrict__ W,
    const float* __restrict__ Bi,
    float* __restrict__ Co)
{
  const int K = 1024, N = 1024;

  __shared__ __align__(16) short sA[128 * 32];
  __shared__ __align__(16) short sB[128 * 32];

  const int t = threadIdx.x;
  const int lane = t & 63, wv = t >> 6;
  const int wm = wv >> 1, wn = wv & 1;
  const int lr = lane & 15, lg = lane >> 4;
  const int m0 = blockIdx.x * 128, n0 = blockIdx.y * 128;

  const int srow = t >> 2;
  const int scol = (t & 3) * 8;

  f32x4 acc[4][4];
#pragma unroll
  for (int m = 0; m < 4; ++m)
#pragma unroll
    for (int n = 0; n < 4; ++n) acc[m][n] = (f32x4){0.f, 0.f, 0.f, 0.f};

  for (int e0 = 0; e0 < K; e0 += 32) {
    __syncthreads();
#pragma unroll
    for (int i = 0; i < 2; ++i) {
      const int row = i * 64 + srow;
      short8 av = *(const short8*)(A + (size_t)(m0 + row) * K + e0 + scol);
      *(short8*)(sA + row * 32 + scol) = av;

      const float* gb = W + (size_t)(n0 + row) * K + e0 + scol;
      float4 b0 = *(const float4*)gb;
      float4 b1 = *(const float4*)(gb + 4);
      short8 bv;
      bv[0] = f2b(b0.x); bv[1] = f2b(b0.y); bv[2] = f2b(b0.z); bv[3] = f2b(b0.w);
      bv[4] = f2b(b1.x); bv[5] = f2b(b1.y); bv[6] = f2b(b1.z); bv[7] = f2b(b1.w);
      *(short8*)(sB + row * 32 + scol) = bv;
    }
    __syncthreads();

    short8 af[4], bf[4];
#pragma unroll
    for (int m = 0; m < 4; ++m)
      af[m] = *(const short8*)(sA + (wm * 64 + m * 16 + lr) * 32 + lg * 8);
#pragma unroll
    for (int n = 0; n < 4; ++n)
      bf[n] = *(const short8*)(sB + (wn * 64 + n * 16 + lr) * 32 + lg * 8);
#pragma unroll
    for (int m = 0; m < 4; ++m)
#pragma unroll
      for (int n = 0; n < 4; ++n)
        acc[m][n] = __builtin_amdgcn_mfma_f32_16x16x32_bf16(af[m], bf[n], acc[m][n], 0, 0, 0);
  }

#pragma unroll
  for (int n = 0; n < 4; ++n) {
    const int gc = n0 + wn * 64 + n * 16 + lr;
    const float bias = Bi[gc];
#pragma unroll
    for (int m = 0; m < 4; ++m) {
      const int gr0 = m0 + wm * 64 + m * 16 + lg * 4;
#pragma unroll
      for (int r = 0; r < 4; ++r)
        Co[(size_t)(gr0 + r) * N + gc] = acc[m][n][r] + bias;
    }
  }
}

// ---------------------------------------------------------------------------
// Sliding-window flash attention. Block = 64 q-rows (4 waves x 16), one head.
// 32-key chunks, online softmax. K read from global (L1/L2); V transposed to
// LDS; P handed off C-layout -> A-layout via padded LDS.
// ---------------------------------------------------------------------------
__global__ __launch_bounds__(256) void attn(
    const unsigned short* __restrict__ Q,
    const unsigned short* __restrict__ Km,
    const unsigned short* __restrict__ Vm,
    unsigned short* __restrict__ AO)
{
  const int q0 = blockIdx.x * 64;
  const int h = blockIdx.y;
  const int t = threadIdx.x;
  const int lane = t & 63, w = t >> 6;
  const int lr = lane & 15, lg = lane >> 4;

  __shared__ __align__(16) short Vt[64 * 40];       // [d][key] padded
  __shared__ __align__(16) short Pl[4 * 16 * 40];   // [64 rows][32+8]

  const int kb0 = (q0 >= WIN) ? (q0 - WIN) : 0;
  const int nch = (q0 + 64 - kb0) >> 5;

  short8 qf[2];
  {
    const unsigned short* qp = Q + (size_t)(q0 + w * 16 + lr) * DM + h * DH + lg * 8;
    qf[0] = *(const short8*)qp;
    qf[1] = *(const short8*)(qp + 32);
  }

  f32x4 o[4];
#pragma unroll
  for (int dt = 0; dt < 4; ++dt) o[dt] = (f32x4){0.f, 0.f, 0.f, 0.f};
  float mrow[4], lrow[4];
#pragma unroll
  for (int r = 0; r < 4; ++r) { mrow[r] = -1e30f; lrow[r] = 0.f; }

  const int vkey = t >> 3;        // 0..31
  const int vd0 = (t & 7) * 8;

  for (int c = 0; c < nch; ++c) {
    const int kb = kb0 + c * 32;
    __syncthreads();   // previous chunk's Vt/Pl consumers done

    // stage V^T chunk: Vt[d][key_local]
    {
      short8 vv = *(const short8*)(Vm + (size_t)(kb + vkey) * DM + h * DH + vd0);
#pragma unroll
      for (int j = 0; j < 8; ++j) Vt[(vd0 + j) * 40 + vkey] = vv[j];
    }

    // QK^T for 32 keys (2 col-tiles x 2 k-steps)
    f32x4 s[2];
    s[0] = (f32x4){0.f, 0.f, 0.f, 0.f};
    s[1] = (f32x4){0.f, 0.f, 0.f, 0.f};
#pragma unroll
    for (int ct = 0; ct < 2; ++ct) {
      const unsigned short* kp = Km + (size_t)(kb + ct * 16 + lr) * DM + h * DH + lg * 8;
      short8 k0 = *(const short8*)kp;
      short8 k1 = *(const short8*)(kp + 32);
      s[ct] = __builtin_amdgcn_mfma_f32_16x16x32_bf16(qf[0], k0, s[ct], 0, 0, 0);
      s[ct] = __builtin_amdgcn_mfma_f32_16x16x32_bf16(qf[1], k1, s[ct], 0, 0, 0);
    }

    // mask + scale; per-row online softmax (rows of this lane: lg*4+r)
    float sv[2][4], pm[4];
    const int qg0 = q0 + w * 16 + lg * 4;
#pragma unroll
    for (int r = 0; r < 4; ++r) {
#pragma unroll
      for (int ct = 0; ct < 2; ++ct) {
        const int key = kb + ct * 16 + lr;
        const int qr = qg0 + r;
        const bool valid = (key <= qr) && (qr - key < WIN);
        sv[ct][r] = valid ? s[ct][r] * 0.125f : -1e30f;
      }
      pm[r] = fmaxf(sv[0][r], sv[1][r]);
    }
#pragma unroll
    for (int off = 1; off < 16; off <<= 1)
#pragma unroll
      for (int r = 0; r < 4; ++r) pm[r] = fmaxf(pm[r], __shfl_xor(pm[r], off, 64));

    float fac[4], rs[4], p[2][4];
#pragma unroll
    for (int r = 0; r < 4; ++r) {
      const float mn = fmaxf(mrow[r], pm[r]);
      fac[r] = __expf(mrow[r] - mn);
      mrow[r] = mn;
      p[0][r] = (sv[0][r] < -1e29f) ? 0.f : __expf(sv[0][r] - mn);
      p[1][r] = (sv[1][r] < -1e29f) ? 0.f : __expf(sv[1][r] - mn);
      rs[r] = p[0][r] + p[1][r];
    }
#pragma unroll
    for (int off = 1; off < 16; off <<= 1)
#pragma unroll
      for (int r = 0; r < 4; ++r) rs[r] += __shfl_xor(rs[r], off, 64);
#pragma unroll
    for (int r = 0; r < 4; ++r) lrow[r] = lrow[r] * fac[r] + rs[r];
#pragma unroll
    for (int dt = 0; dt < 4; ++dt)
#pragma unroll
      for (int r = 0; r < 4; ++r) o[dt][r] *= fac[r];

    // P (C layout) -> LDS
#pragma unroll
    for (int r = 0; r < 4; ++r)
#pragma unroll
      for (int ct = 0; ct < 2; ++ct)
        Pl[(w * 16 + lg * 4 + r) * 40 + ct * 16 + lr] = (short)f2b(p[ct][r]);

    __syncthreads();   // Vt staged + Pl visible

    // PV: A = P (row=lr, k=key slot), B = Vt (col=d, k=key slot)
    short8 pa = *(const short8*)(Pl + (w * 16 + lr) * 40 + lg * 8);
#pragma unroll
    for (int dt = 0; dt < 4; ++dt) {
      short8 vb = *(const short8*)(Vt + (dt * 16 + lr) * 40 + lg * 8);
      o[dt] = __builtin_amdgcn_mfma_f32_16x16x32_bf16(pa, vb, o[dt], 0, 0, 0);
    }
  }

  // epilogue: normalize, store bf16
  float inv[4];
#pragma unroll
  for (int r = 0; r < 4; ++r) inv[r] = 1.f / lrow[r];
#pragma unroll
  for (int dt = 0; dt < 4; ++dt)
#pragma unroll
    for (int r = 0; r < 4; ++r)
      AO[(size_t)(q0 + w * 16 + lg * 4 + r) * DM + h * DH + dt * 16 + lr] =
          f2b(o[dt][r] * inv[r]);
}

// ---------------------------------------------------------------------------
extern "C" void kernel_launch(void* const* d_in, const int* in_sizes, int n_in,
                              void* d_out, int out_size, void* d_ws, size_t ws_size,
                              hipStream_t stream) {
  const float* x  = (const float*)d_in[0];
  const float* qw = (const float*)d_in[1];
  const float* qb = (const float*)d_in[2];
  const float* kw = (const float*)d_in[3];
  const float* kb = (const float*)d_in[4];
  const float* vw = (const float*)d_in[5];
  const float* vb = (const float*)d_in[6];
  const float* ow = (const float*)d_in[7];
  const float* ob = (const float*)d_in[8];

  unsigned short* Qb  = (unsigned short*)d_ws;
  unsigned short* Kb  = Qb + (size_t)S_LEN * DM;
  unsigned short* Vb  = Kb + (size_t)S_LEN * DM;
  unsigned short* AOb = Vb + (size_t)S_LEN * DM;

  gemm_qkv<<<dim3(32, 8, 3), 256, 0, stream>>>(x, qw, kw, vw, qb, kb, vb, Qb, Kb, Vb);
  attn<<<dim3(S_LEN / 64, NH), 256, 0, stream>>>(Qb, Kb, Vb, AOb);
  gemm_out<<<dim3(32, 8), 256, 0, stream>>>(AOb, ow, ob, (float*)d_out);
}

// Round 2
// 118.164 us; speedup vs baseline: 1.0880x; 1.0880x over previous
//
#include <hip/hip_runtime.h>

typedef __attribute__((ext_vector_type(4))) float f32x4;
typedef __attribute__((ext_vector_type(8))) short short8;

#define S_LEN 4096
#define DM    1024
#define NH    16
#define DH    64
#define WIN   256

__device__ inline unsigned short f2b(float f) {
  unsigned int x = __float_as_uint(f);
  unsigned int r = (x + 0x7fffu + ((x >> 16) & 1u)) >> 16;
  return (unsigned short)r;
}

__device__ inline void gload_lds16(const void* g, void* l) {
  __builtin_amdgcn_global_load_lds(
      (const __attribute__((address_space(1))) void*)g,
      (__attribute__((address_space(3))) void*)l, 16, 0, 0);
}

// ---------------------------------------------------------------------------
// Convert X and the 4 weight matrices f32 -> bf16.
// y=0: X (524288 x8-groups); y=1..4: weights (131072 x8-groups each).
// ---------------------------------------------------------------------------
__global__ __launch_bounds__(256) void cvt_all(
    const float* __restrict__ x,
    const float* __restrict__ qw, const float* __restrict__ kw,
    const float* __restrict__ vw, const float* __restrict__ ow,
    unsigned short* __restrict__ Xb, unsigned short* __restrict__ Wb)
{
  const int y = blockIdx.y;
  const float* src;
  unsigned short* dst;
  int n8;
  if (y == 0) { src = x; dst = Xb; n8 = (S_LEN * DM) / 8; }
  else {
    src = (y == 1) ? qw : (y == 2) ? kw : (y == 3) ? vw : ow;
    dst = Wb + (size_t)(y - 1) * DM * DM;
    n8 = (DM * DM) / 8;
  }
  const int i = blockIdx.x * 256 + threadIdx.x;
  if (i >= n8) return;
  const float4* s4 = (const float4*)src + (size_t)i * 2;
  float4 a = s4[0], b = s4[1];
  short8 v;
  v[0] = f2b(a.x); v[1] = f2b(a.y); v[2] = f2b(a.z); v[3] = f2b(a.w);
  v[4] = f2b(b.x); v[5] = f2b(b.y); v[6] = f2b(b.z); v[7] = f2b(b.w);
  *(short8*)(dst + (size_t)i * 8) = v;
}

// ---------------------------------------------------------------------------
// m97-structure GEMM: C[M][1024] = A[M][1024] x B^T (B stored [N][1024]) + bias
// 128x128 tile, BK=64, 4 waves (2x2), global_load_lds dwordx4 staging,
// linear LDS, 2 barriers per K-tile. z selects weight slice / bias / output.
// ---------------------------------------------------------------------------
template<bool F32OUT>
__global__ __launch_bounds__(256) void gemm_bt(
    const unsigned short* __restrict__ A,
    const unsigned short* __restrict__ Wb,   // base of weight slices
    const float* __restrict__ b0, const float* __restrict__ b1, const float* __restrict__ b2,
    unsigned short* __restrict__ Obf,        // bf16 out base (z-strided)
    float* __restrict__ Of)                  // f32 out (z==0 only)
{
  const int z = blockIdx.z;
  const unsigned short* B = Wb + (size_t)z * DM * DM;
  const float* bias = (z == 0) ? b0 : (z == 1) ? b1 : b2;
  unsigned short* O = Obf + (size_t)z * S_LEN * DM;

  __shared__ __align__(16) unsigned short sA[128 * 64];
  __shared__ __align__(16) unsigned short sB[128 * 64];

  const int t = threadIdx.x;
  const int lane = t & 63, w = t >> 6;
  const int wm = w >> 1, wn = w & 1;
  const int lr = lane & 15, lg = lane >> 4;
  const int m0 = blockIdx.x * 128, n0 = blockIdx.y * 128;
  const int r8 = lane >> 3, c8 = (lane & 7) * 8;

  f32x4 acc[4][4];
#pragma unroll
  for (int m = 0; m < 4; ++m)
#pragma unroll
    for (int n = 0; n < 4; ++n) acc[m][n] = (f32x4){0.f, 0.f, 0.f, 0.f};

  // per-lane global srcs; wave-uniform LDS dests (8 rows = 1024B per load)
  const unsigned short* ga0 = A + (size_t)(m0 + w * 32 + r8) * DM + c8;
  const unsigned short* gb0 = B + (size_t)(n0 + w * 32 + r8) * DM + c8;
  unsigned short* la0 = sA + (w * 32) * 64;
  unsigned short* lb0 = sB + (w * 32) * 64;

  for (int e0 = 0; e0 < DM; e0 += 64) {
    __syncthreads();
#pragma unroll
    for (int i = 0; i < 4; ++i) {
      gload_lds16(ga0 + (size_t)(i * 8) * DM + e0, la0 + i * 8 * 64);
      gload_lds16(gb0 + (size_t)(i * 8) * DM + e0, lb0 + i * 8 * 64);
    }
    __syncthreads();   // compiler inserts vmcnt(0) drain before barrier

#pragma unroll
    for (int kk = 0; kk < 2; ++kk) {
      short8 af[4], bf[4];
#pragma unroll
      for (int m = 0; m < 4; ++m)
        af[m] = *(const short8*)(sA + (wm * 64 + m * 16 + lr) * 64 + kk * 32 + lg * 8);
#pragma unroll
      for (int n = 0; n < 4; ++n)
        bf[n] = *(const short8*)(sB + (wn * 64 + n * 16 + lr) * 64 + kk * 32 + lg * 8);
#pragma unroll
      for (int m = 0; m < 4; ++m)
#pragma unroll
        for (int n = 0; n < 4; ++n)
          acc[m][n] = __builtin_amdgcn_mfma_f32_16x16x32_bf16(af[m], bf[n], acc[m][n], 0, 0, 0);
    }
  }

#pragma unroll
  for (int n = 0; n < 4; ++n) {
    const int gc = n0 + wn * 64 + n * 16 + lr;
    const float bv = bias[gc];
#pragma unroll
    for (int m = 0; m < 4; ++m) {
      const int gr0 = m0 + wm * 64 + m * 16 + lg * 4;
#pragma unroll
      for (int r = 0; r < 4; ++r) {
        const float val = acc[m][n][r] + bv;
        if (F32OUT) Of[(size_t)(gr0 + r) * DM + gc] = val;
        else        O[(size_t)(gr0 + r) * DM + gc] = f2b(val);
      }
    }
  }
}

// ---------------------------------------------------------------------------
// Sliding-window flash attention (unchanged this round).
// ---------------------------------------------------------------------------
__global__ __launch_bounds__(256) void attn(
    const unsigned short* __restrict__ Q,
    const unsigned short* __restrict__ Km,
    const unsigned short* __restrict__ Vm,
    unsigned short* __restrict__ AO)
{
  const int q0 = blockIdx.x * 64;
  const int h = blockIdx.y;
  const int t = threadIdx.x;
  const int lane = t & 63, w = t >> 6;
  const int lr = lane & 15, lg = lane >> 4;

  __shared__ __align__(16) short Vt[64 * 40];       // [d][key] padded
  __shared__ __align__(16) short Pl[4 * 16 * 40];   // [64 rows][32+8]

  const int kb0 = (q0 >= WIN) ? (q0 - WIN) : 0;
  const int nch = (q0 + 64 - kb0) >> 5;

  short8 qf[2];
  {
    const unsigned short* qp = Q + (size_t)(q0 + w * 16 + lr) * DM + h * DH + lg * 8;
    qf[0] = *(const short8*)qp;
    qf[1] = *(const short8*)(qp + 32);
  }

  f32x4 o[4];
#pragma unroll
  for (int dt = 0; dt < 4; ++dt) o[dt] = (f32x4){0.f, 0.f, 0.f, 0.f};
  float mrow[4], lrow[4];
#pragma unroll
  for (int r = 0; r < 4; ++r) { mrow[r] = -1e30f; lrow[r] = 0.f; }

  const int vkey = t >> 3;        // 0..31
  const int vd0 = (t & 7) * 8;

  for (int c = 0; c < nch; ++c) {
    const int kb = kb0 + c * 32;
    __syncthreads();

    {
      short8 vv = *(const short8*)(Vm + (size_t)(kb + vkey) * DM + h * DH + vd0);
#pragma unroll
      for (int j = 0; j < 8; ++j) Vt[(vd0 + j) * 40 + vkey] = vv[j];
    }

    f32x4 s[2];
    s[0] = (f32x4){0.f, 0.f, 0.f, 0.f};
    s[1] = (f32x4){0.f, 0.f, 0.f, 0.f};
#pragma unroll
    for (int ct = 0; ct < 2; ++ct) {
      const unsigned short* kp = Km + (size_t)(kb + ct * 16 + lr) * DM + h * DH + lg * 8;
      short8 k0 = *(const short8*)kp;
      short8 k1 = *(const short8*)(kp + 32);
      s[ct] = __builtin_amdgcn_mfma_f32_16x16x32_bf16(qf[0], k0, s[ct], 0, 0, 0);
      s[ct] = __builtin_amdgcn_mfma_f32_16x16x32_bf16(qf[1], k1, s[ct], 0, 0, 0);
    }

    float sv[2][4], pm[4];
    const int qg0 = q0 + w * 16 + lg * 4;
#pragma unroll
    for (int r = 0; r < 4; ++r) {
#pragma unroll
      for (int ct = 0; ct < 2; ++ct) {
        const int key = kb + ct * 16 + lr;
        const int qr = qg0 + r;
        const bool valid = (key <= qr) && (qr - key < WIN);
        sv[ct][r] = valid ? s[ct][r] * 0.125f : -1e30f;
      }
      pm[r] = fmaxf(sv[0][r], sv[1][r]);
    }
#pragma unroll
    for (int off = 1; off < 16; off <<= 1)
#pragma unroll
      for (int r = 0; r < 4; ++r) pm[r] = fmaxf(pm[r], __shfl_xor(pm[r], off, 64));

    float fac[4], rs[4], p[2][4];
#pragma unroll
    for (int r = 0; r < 4; ++r) {
      const float mn = fmaxf(mrow[r], pm[r]);
      fac[r] = __expf(mrow[r] - mn);
      mrow[r] = mn;
      p[0][r] = (sv[0][r] < -1e29f) ? 0.f : __expf(sv[0][r] - mn);
      p[1][r] = (sv[1][r] < -1e29f) ? 0.f : __expf(sv[1][r] - mn);
      rs[r] = p[0][r] + p[1][r];
    }
#pragma unroll
    for (int off = 1; off < 16; off <<= 1)
#pragma unroll
      for (int r = 0; r < 4; ++r) rs[r] += __shfl_xor(rs[r], off, 64);
#pragma unroll
    for (int r = 0; r < 4; ++r) lrow[r] = lrow[r] * fac[r] + rs[r];
#pragma unroll
    for (int dt = 0; dt < 4; ++dt)
#pragma unroll
      for (int r = 0; r < 4; ++r) o[dt][r] *= fac[r];

#pragma unroll
    for (int r = 0; r < 4; ++r)
#pragma unroll
      for (int ct = 0; ct < 2; ++ct)
        Pl[(w * 16 + lg * 4 + r) * 40 + ct * 16 + lr] = (short)f2b(p[ct][r]);

    __syncthreads();

    short8 pa = *(const short8*)(Pl + (w * 16 + lr) * 40 + lg * 8);
#pragma unroll
    for (int dt = 0; dt < 4; ++dt) {
      short8 vb = *(const short8*)(Vt + (dt * 16 + lr) * 40 + lg * 8);
      o[dt] = __builtin_amdgcn_mfma_f32_16x16x32_bf16(pa, vb, o[dt], 0, 0, 0);
    }
  }

  float inv[4];
#pragma unroll
  for (int r = 0; r < 4; ++r) inv[r] = 1.f / lrow[r];
#pragma unroll
  for (int dt = 0; dt < 4; ++dt)
#pragma unroll
    for (int r = 0; r < 4; ++r)
      AO[(size_t)(q0 + w * 16 + lg * 4 + r) * DM + h * DH + dt * 16 + lr] =
          f2b(o[dt][r] * inv[r]);
}

// ---------------------------------------------------------------------------
extern "C" void kernel_launch(void* const* d_in, const int* in_sizes, int n_in,
                              void* d_out, int out_size, void* d_ws, size_t ws_size,
                              hipStream_t stream) {
  const float* x  = (const float*)d_in[0];
  const float* qw = (const float*)d_in[1];
  const float* qb = (const float*)d_in[2];
  const float* kw = (const float*)d_in[3];
  const float* kb = (const float*)d_in[4];
  const float* vw = (const float*)d_in[5];
  const float* vb = (const float*)d_in[6];
  const float* ow = (const float*)d_in[7];
  const float* ob = (const float*)d_in[8];

  const size_t SD = (size_t)S_LEN * DM;     // 4.19M elems
  unsigned short* Qb  = (unsigned short*)d_ws;         // also base for K,V (z-strided)
  unsigned short* Kb  = Qb + SD;
  unsigned short* Vb  = Kb + SD;
  unsigned short* AOb = Vb + SD;
  unsigned short* Xb  = AOb + SD;
  unsigned short* Wcv = Xb + SD;            // 4 weight slices, bf16

  cvt_all<<<dim3(2048, 5), 256, 0, stream>>>(x, qw, kw, vw, ow, Xb, Wcv);
  // QKV: z in {0,1,2} selects weight slice, bias, output slice (Qb base)
  gemm_bt<false><<<dim3(32, 8, 3), 256, 0, stream>>>(Xb, Wcv, qb, kb, vb, Qb, nullptr);
  attn<<<dim3(S_LEN / 64, NH), 256, 0, stream>>>(Qb, Kb, Vb, AOb);
  // O-proj: weight slice 3, f32 out
  gemm_bt<true><<<dim3(32, 8, 1), 256, 0, stream>>>(AOb, Wcv + (size_t)3 * DM * DM,
                                                    ob, ob, ob, nullptr, (float*)d_out);
}

// Round 3
// 110.380 us; speedup vs baseline: 1.1647x; 1.0705x over previous
//
#include <hip/hip_runtime.h>

typedef __attribute__((ext_vector_type(4))) float f32x4;
typedef __attribute__((ext_vector_type(8))) short short8;

#define S_LEN 4096
#define DM    1024
#define NH    16
#define DH    64
#define WIN   256

__device__ inline unsigned short f2b(float f) {
  unsigned int x = __float_as_uint(f);
  unsigned int r = (x + 0x7fffu + ((x >> 16) & 1u)) >> 16;
  return (unsigned short)r;
}

__device__ inline void gload_lds16(const void* g, void* l) {
  __builtin_amdgcn_global_load_lds(
      (const __attribute__((address_space(1))) void*)g,
      (__attribute__((address_space(3))) void*)l, 16, 0, 0);
}

// ---------------------------------------------------------------------------
// Convert X and the 4 weight matrices f32 -> bf16.
// ---------------------------------------------------------------------------
__global__ __launch_bounds__(256) void cvt_all(
    const float* __restrict__ x,
    const float* __restrict__ qw, const float* __restrict__ kw,
    const float* __restrict__ vw, const float* __restrict__ ow,
    unsigned short* __restrict__ Xb, unsigned short* __restrict__ Wb)
{
  const int y = blockIdx.y;
  const float* src;
  unsigned short* dst;
  int n8;
  if (y == 0) { src = x; dst = Xb; n8 = (S_LEN * DM) / 8; }
  else {
    src = (y == 1) ? qw : (y == 2) ? kw : (y == 3) ? vw : ow;
    dst = Wb + (size_t)(y - 1) * DM * DM;
    n8 = (DM * DM) / 8;
  }
  const int i = blockIdx.x * 256 + threadIdx.x;
  if (i >= n8) return;
  const float4* s4 = (const float4*)src + (size_t)i * 2;
  float4 a = s4[0], b = s4[1];
  short8 v;
  v[0] = f2b(a.x); v[1] = f2b(a.y); v[2] = f2b(a.z); v[3] = f2b(a.w);
  v[4] = f2b(b.x); v[5] = f2b(b.y); v[6] = f2b(b.z); v[7] = f2b(b.w);
  *(short8*)(dst + (size_t)i * 8) = v;
}

// ---------------------------------------------------------------------------
// 2-phase double-buffered GEMM: C[M][1024] = A x B^T + bias.
// 128x128 tile, BK=64, 4 waves (2x2). STAGE(t+1) issued BEFORE compute(t);
// one vmcnt(0)+barrier per K-tile (from __syncthreads). Static buffers,
// fully unrolled x2 so all LDS addresses are compile-time.
// ---------------------------------------------------------------------------
struct GemmCtx {
  const unsigned short* ga0;
  const unsigned short* gb0;
  unsigned short* la0;
  unsigned short* lb0;
  const unsigned short* sa;
  const unsigned short* sb;
  int wm, wn, lr, lg;
};

__device__ __forceinline__ void stage_tile(const GemmCtx& c,
    unsigned short* laB, unsigned short* lbB, int e0) {
#pragma unroll
  for (int i = 0; i < 4; ++i) {
    gload_lds16(c.ga0 + (size_t)(i * 8) * DM + e0, laB + i * 8 * 64);
    gload_lds16(c.gb0 + (size_t)(i * 8) * DM + e0, lbB + i * 8 * 64);
  }
}

__device__ __forceinline__ void compute_tile(const GemmCtx& c,
    const unsigned short* saB, const unsigned short* sbB, f32x4 acc[4][4]) {
#pragma unroll
  for (int kk = 0; kk < 2; ++kk) {
    short8 af[4], bf[4];
#pragma unroll
    for (int m = 0; m < 4; ++m)
      af[m] = *(const short8*)(saB + (c.wm * 64 + m * 16 + c.lr) * 64 + kk * 32 + c.lg * 8);
#pragma unroll
    for (int n = 0; n < 4; ++n)
      bf[n] = *(const short8*)(sbB + (c.wn * 64 + n * 16 + c.lr) * 64 + kk * 32 + c.lg * 8);
#pragma unroll
    for (int m = 0; m < 4; ++m)
#pragma unroll
      for (int n = 0; n < 4; ++n)
        acc[m][n] = __builtin_amdgcn_mfma_f32_16x16x32_bf16(af[m], bf[n], acc[m][n], 0, 0, 0);
  }
}

template<bool F32OUT>
__global__ __launch_bounds__(256) void gemm_bt(
    const unsigned short* __restrict__ A,
    const unsigned short* __restrict__ Wb,
    const float* __restrict__ b0, const float* __restrict__ b1, const float* __restrict__ b2,
    unsigned short* __restrict__ Obf,
    float* __restrict__ Of)
{
  const int z = blockIdx.z;
  const unsigned short* B = Wb + (size_t)z * DM * DM;
  const float* bias = (z == 0) ? b0 : (z == 1) ? b1 : b2;
  unsigned short* O = Obf + (size_t)z * S_LEN * DM;

  __shared__ __align__(16) unsigned short sA0[128 * 64];
  __shared__ __align__(16) unsigned short sB0[128 * 64];
  __shared__ __align__(16) unsigned short sA1[128 * 64];
  __shared__ __align__(16) unsigned short sB1[128 * 64];

  const int t = threadIdx.x;
  const int lane = t & 63, w = t >> 6;
  const int m0 = blockIdx.x * 128, n0 = blockIdx.y * 128;
  const int r8 = lane >> 3, c8 = (lane & 7) * 8;

  GemmCtx c;
  c.wm = (w >> 1);
  c.wn = (w & 1);
  c.lr = lane & 15;
  c.lg = lane >> 4;
  c.ga0 = A + (size_t)(m0 + w * 32 + r8) * DM + c8;
  c.gb0 = B + (size_t)(n0 + w * 32 + r8) * DM + c8;
  c.la0 = nullptr; c.lb0 = nullptr;

  unsigned short* la0 = sA0 + (w * 32) * 64;
  unsigned short* lb0 = sB0 + (w * 32) * 64;
  unsigned short* la1 = sA1 + (w * 32) * 64;
  unsigned short* lb1 = sB1 + (w * 32) * 64;

  f32x4 acc[4][4];
#pragma unroll
  for (int m = 0; m < 4; ++m)
#pragma unroll
    for (int n = 0; n < 4; ++n) acc[m][n] = (f32x4){0.f, 0.f, 0.f, 0.f};

  // prologue
  stage_tile(c, la0, lb0, 0);
  __syncthreads();                       // vmcnt(0) drain + barrier

  // 16 K-tiles of 64: stages 1..14 + computes 0..13 in 7 double-iterations
#pragma unroll 1
  for (int kt = 0; kt < 14; kt += 2) {
    stage_tile(c, la1, lb1, (kt + 1) * 64);
    compute_tile(c, sA0, sB0, acc);
    __syncthreads();
    stage_tile(c, la0, lb0, (kt + 2) * 64);
    compute_tile(c, sA1, sB1, acc);
    __syncthreads();
  }
  stage_tile(c, la1, lb1, 15 * 64);
  compute_tile(c, sA0, sB0, acc);
  __syncthreads();
  compute_tile(c, sA1, sB1, acc);

#pragma unroll
  for (int n = 0; n < 4; ++n) {
    const int gc = n0 + c.wn * 64 + n * 16 + c.lr;
    const float bv = bias[gc];
#pragma unroll
    for (int m = 0; m < 4; ++m) {
      const int gr0 = m0 + c.wm * 64 + m * 16 + c.lg * 4;
#pragma unroll
      for (int r = 0; r < 4; ++r) {
        const float val = acc[m][n][r] + bv;
        if (F32OUT) Of[(size_t)(gr0 + r) * DM + gc] = val;
        else        O[(size_t)(gr0 + r) * DM + gc] = f2b(val);
      }
    }
  }
}

// ---------------------------------------------------------------------------
// Sliding-window flash attention (unchanged this round).
// ---------------------------------------------------------------------------
__global__ __launch_bounds__(256) void attn(
    const unsigned short* __restrict__ Q,
    const unsigned short* __restrict__ Km,
    const unsigned short* __restrict__ Vm,
    unsigned short* __restrict__ AO)
{
  const int q0 = blockIdx.x * 64;
  const int h = blockIdx.y;
  const int t = threadIdx.x;
  const int lane = t & 63, w = t >> 6;
  const int lr = lane & 15, lg = lane >> 4;

  __shared__ __align__(16) short Vt[64 * 40];
  __shared__ __align__(16) short Pl[4 * 16 * 40];

  const int kb0 = (q0 >= WIN) ? (q0 - WIN) : 0;
  const int nch = (q0 + 64 - kb0) >> 5;

  short8 qf[2];
  {
    const unsigned short* qp = Q + (size_t)(q0 + w * 16 + lr) * DM + h * DH + lg * 8;
    qf[0] = *(const short8*)qp;
    qf[1] = *(const short8*)(qp + 32);
  }

  f32x4 o[4];
#pragma unroll
  for (int dt = 0; dt < 4; ++dt) o[dt] = (f32x4){0.f, 0.f, 0.f, 0.f};
  float mrow[4], lrow[4];
#pragma unroll
  for (int r = 0; r < 4; ++r) { mrow[r] = -1e30f; lrow[r] = 0.f; }

  const int vkey = t >> 3;
  const int vd0 = (t & 7) * 8;

  for (int ch = 0; ch < nch; ++ch) {
    const int kb = kb0 + ch * 32;
    __syncthreads();

    {
      short8 vv = *(const short8*)(Vm + (size_t)(kb + vkey) * DM + h * DH + vd0);
#pragma unroll
      for (int j = 0; j < 8; ++j) Vt[(vd0 + j) * 40 + vkey] = vv[j];
    }

    f32x4 s[2];
    s[0] = (f32x4){0.f, 0.f, 0.f, 0.f};
    s[1] = (f32x4){0.f, 0.f, 0.f, 0.f};
#pragma unroll
    for (int ct = 0; ct < 2; ++ct) {
      const unsigned short* kp = Km + (size_t)(kb + ct * 16 + lr) * DM + h * DH + lg * 8;
      short8 k0 = *(const short8*)kp;
      short8 k1 = *(const short8*)(kp + 32);
      s[ct] = __builtin_amdgcn_mfma_f32_16x16x32_bf16(qf[0], k0, s[ct], 0, 0, 0);
      s[ct] = __builtin_amdgcn_mfma_f32_16x16x32_bf16(qf[1], k1, s[ct], 0, 0, 0);
    }

    float sv[2][4], pm[4];
    const int qg0 = q0 + w * 16 + lg * 4;
#pragma unroll
    for (int r = 0; r < 4; ++r) {
#pragma unroll
      for (int ct = 0; ct < 2; ++ct) {
        const int key = kb + ct * 16 + lr;
        const int qr = qg0 + r;
        const bool valid = (key <= qr) && (qr - key < WIN);
        sv[ct][r] = valid ? s[ct][r] * 0.125f : -1e30f;
      }
      pm[r] = fmaxf(sv[0][r], sv[1][r]);
    }
#pragma unroll
    for (int off = 1; off < 16; off <<= 1)
#pragma unroll
      for (int r = 0; r < 4; ++r) pm[r] = fmaxf(pm[r], __shfl_xor(pm[r], off, 64));

    float fac[4], rs[4], p[2][4];
#pragma unroll
    for (int r = 0; r < 4; ++r) {
      const float mn = fmaxf(mrow[r], pm[r]);
      fac[r] = __expf(mrow[r] - mn);
      mrow[r] = mn;
      p[0][r] = (sv[0][r] < -1e29f) ? 0.f : __expf(sv[0][r] - mn);
      p[1][r] = (sv[1][r] < -1e29f) ? 0.f : __expf(sv[1][r] - mn);
      rs[r] = p[0][r] + p[1][r];
    }
#pragma unroll
    for (int off = 1; off < 16; off <<= 1)
#pragma unroll
      for (int r = 0; r < 4; ++r) rs[r] += __shfl_xor(rs[r], off, 64);
#pragma unroll
    for (int r = 0; r < 4; ++r) lrow[r] = lrow[r] * fac[r] + rs[r];
#pragma unroll
    for (int dt = 0; dt < 4; ++dt)
#pragma unroll
      for (int r = 0; r < 4; ++r) o[dt][r] *= fac[r];

#pragma unroll
    for (int r = 0; r < 4; ++r)
#pragma unroll
      for (int ct = 0; ct < 2; ++ct)
        Pl[(w * 16 + lg * 4 + r) * 40 + ct * 16 + lr] = (short)f2b(p[ct][r]);

    __syncthreads();

    short8 pa = *(const short8*)(Pl + (w * 16 + lr) * 40 + lg * 8);
#pragma unroll
    for (int dt = 0; dt < 4; ++dt) {
      short8 vb = *(const short8*)(Vt + (dt * 16 + lr) * 40 + lg * 8);
      o[dt] = __builtin_amdgcn_mfma_f32_16x16x32_bf16(pa, vb, o[dt], 0, 0, 0);
    }
  }

  float inv[4];
#pragma unroll
  for (int r = 0; r < 4; ++r) inv[r] = 1.f / lrow[r];
#pragma unroll
  for (int dt = 0; dt < 4; ++dt)
#pragma unroll
    for (int r = 0; r < 4; ++r)
      AO[(size_t)(q0 + w * 16 + lg * 4 + r) * DM + h * DH + dt * 16 + lr] =
          f2b(o[dt][r] * inv[r]);
}

// ---------------------------------------------------------------------------
extern "C" void kernel_launch(void* const* d_in, const int* in_sizes, int n_in,
                              void* d_out, int out_size, void* d_ws, size_t ws_size,
                              hipStream_t stream) {
  const float* x  = (const float*)d_in[0];
  const float* qw = (const float*)d_in[1];
  const float* qb = (const float*)d_in[2];
  const float* kw = (const float*)d_in[3];
  const float* kb = (const float*)d_in[4];
  const float* vw = (const float*)d_in[5];
  const float* vb = (const float*)d_in[6];
  const float* ow = (const float*)d_in[7];
  const float* ob = (const float*)d_in[8];

  const size_t SD = (size_t)S_LEN * DM;
  unsigned short* Qb  = (unsigned short*)d_ws;
  unsigned short* Kb  = Qb + SD;
  unsigned short* Vb  = Kb + SD;
  unsigned short* AOb = Vb + SD;
  unsigned short* Xb  = AOb + SD;
  unsigned short* Wcv = Xb + SD;

  cvt_all<<<dim3(2048, 5), 256, 0, stream>>>(x, qw, kw, vw, ow, Xb, Wcv);
  gemm_bt<false><<<dim3(32, 8, 3), 256, 0, stream>>>(Xb, Wcv, qb, kb, vb, Qb, nullptr);
  attn<<<dim3(S_LEN / 64, NH), 256, 0, stream>>>(Qb, Kb, Vb, AOb);
  gemm_bt<true><<<dim3(32, 8, 1), 256, 0, stream>>>(AOb, Wcv + (size_t)3 * DM * DM,
                                                    ob, ob, ob, nullptr, (float*)d_out);
}

// Round 4
// 99.960 us; speedup vs baseline: 1.2861x; 1.1042x over previous
//
#include <hip/hip_runtime.h>

typedef __attribute__((ext_vector_type(4))) float f32x4;
typedef __attribute__((ext_vector_type(8))) short short8;

#define S_LEN 4096
#define DM    1024
#define NH    16
#define DH    64
#define WIN   256

__device__ inline unsigned short f2b(float f) {
  unsigned int x = __float_as_uint(f);
  unsigned int r = (x + 0x7fffu + ((x >> 16) & 1u)) >> 16;
  return (unsigned short)r;
}

__device__ inline void gload_lds16(const void* g, void* l) {
  __builtin_amdgcn_global_load_lds(
      (const __attribute__((address_space(1))) void*)g,
      (__attribute__((address_space(3))) void*)l, 16, 0, 0);
}

// ---------------------------------------------------------------------------
// Convert X and the 4 weight matrices f32 -> bf16.
// ---------------------------------------------------------------------------
__global__ __launch_bounds__(256) void cvt_all(
    const float* __restrict__ x,
    const float* __restrict__ qw, const float* __restrict__ kw,
    const float* __restrict__ vw, const float* __restrict__ ow,
    unsigned short* __restrict__ Xb, unsigned short* __restrict__ Wb)
{
  const int y = blockIdx.y;
  const float* src;
  unsigned short* dst;
  int n8;
  if (y == 0) { src = x; dst = Xb; n8 = (S_LEN * DM) / 8; }
  else {
    src = (y == 1) ? qw : (y == 2) ? kw : (y == 3) ? vw : ow;
    dst = Wb + (size_t)(y - 1) * DM * DM;
    n8 = (DM * DM) / 8;
  }
  const int i = blockIdx.x * 256 + threadIdx.x;
  if (i >= n8) return;
  const float4* s4 = (const float4*)src + (size_t)i * 2;
  float4 a = s4[0], b = s4[1];
  short8 v;
  v[0] = f2b(a.x); v[1] = f2b(a.y); v[2] = f2b(a.z); v[3] = f2b(a.w);
  v[4] = f2b(b.x); v[5] = f2b(b.y); v[6] = f2b(b.z); v[7] = f2b(b.w);
  *(short8*)(dst + (size_t)i * 8) = v;
}

// ---------------------------------------------------------------------------
// Deep-pipelined GEMM: C = A x B^T + bias.  BK=64, double-buffered LDS with
// COUNTED vmcnt (loads stay in flight across barriers), conflict-free LDS
// swizzle (col bits 4-6 ^= row bits 0-2; applied to the pre-swizzled GLOBAL
// source since global_load_lds writes linearly), setprio around MFMA.
// qkv: 256x256 tile, 8 waves.  out: 128x128 tile, 4 waves.
// ---------------------------------------------------------------------------
#define PIPE_WAIT8  asm volatile("s_waitcnt vmcnt(8)" ::: "memory")
#define PIPE_WAIT0  asm volatile("s_waitcnt vmcnt(0)" ::: "memory")
#define PIPE_BAR    do { __builtin_amdgcn_s_barrier(); __builtin_amdgcn_sched_barrier(0); } while (0)
#define PIPE_ENDBAR do { __builtin_amdgcn_sched_barrier(0); __builtin_amdgcn_s_barrier(); \
                         __builtin_amdgcn_sched_barrier(0); } while (0)

template<int BM, int BN, int NWM, int NWN, bool F32OUT>
__global__ __launch_bounds__(NWM* NWN * 64, 1) void gemm_bt(
    const unsigned short* __restrict__ A,
    const unsigned short* __restrict__ Wb,
    const float* __restrict__ b0, const float* __restrict__ b1, const float* __restrict__ b2,
    unsigned short* __restrict__ Obf,
    float* __restrict__ Of)
{
  constexpr int THREADS = NWM * NWN * 64;
  constexpr int MR = BM / (NWM * 16);
  constexpr int NR = BN / (NWN * 16);
  constexpr int RSM = BM / NWM;
  constexpr int RSN = BN / NWN;
  constexpr int REG = BM * 64;       // elems per LDS region (BM == BN)
  static_assert(BM == BN, "");
  static_assert((BM * 64 * 2) / (THREADS * 16) == 4, "4 staging rounds");

  const int z = blockIdx.z;
  const unsigned short* Bmat = Wb + (size_t)z * DM * DM;
  const float* bias = (z == 0) ? b0 : (z == 1) ? b1 : b2;
  unsigned short* O = Obf + (size_t)z * S_LEN * DM;

  __shared__ __align__(16) unsigned short LDS[4 * REG];  // A0,A1,B0,B1
  unsigned short* A0 = LDS;
  unsigned short* A1 = LDS + REG;
  unsigned short* B0 = LDS + 2 * REG;
  unsigned short* B1 = LDS + 3 * REG;

  const int t = threadIdx.x;
  const int lane = t & 63, w = t >> 6;
  const int wm = w / NWN, wn = w % NWN;
  const int lr = lane & 15, lg = lane >> 4;
  const int m0 = blockIdx.x * BM, n0 = blockIdx.y * BN;

  // staging precompute: 4 rounds; wave-uniform LDS base, per-lane swizzled src
  int srow[4], scol[4], sbase[4];
#pragma unroll
  for (int i = 0; i < 4; ++i) {
    const int bo = (i * THREADS + w * 64) * 16;   // wave-uniform byte base
    const int o = bo + lane * 16;                 // this lane's dest byte
    const int row = o >> 7, colb = o & 127;
    const int colp = colb ^ ((row & 3) << 4) ^ (((row >> 2) & 1) << 6);
    srow[i] = row; scol[i] = colp >> 1; sbase[i] = bo >> 1;
  }

#define STAGE(e0, lA, lB)                                                           \
  do {                                                                              \
    _Pragma("unroll") for (int i = 0; i < 4; ++i) {                                 \
      gload_lds16(A + (size_t)(m0 + srow[i]) * DM + (e0) + scol[i], (lA) + sbase[i]); \
      gload_lds16(Bmat + (size_t)(n0 + srow[i]) * DM + (e0) + scol[i], (lB) + sbase[i]); \
    }                                                                               \
  } while (0)

  f32x4 acc[MR][NR];
#pragma unroll
  for (int m = 0; m < MR; ++m)
#pragma unroll
    for (int n = 0; n < NR; ++n) acc[m][n] = (f32x4){0.f, 0.f, 0.f, 0.f};

  const int xor6l = ((lr >> 2) & 1) << 6;
  const int xor45 = (lg << 4) ^ ((lr & 3) << 4);

#define COMPUTE(sAp, sBp)                                                           \
  do {                                                                              \
    _Pragma("unroll") for (int kk = 0; kk < 2; ++kk) {                              \
      const int coff = ((kk << 6) ^ xor6l) + xor45;                                 \
      short8 af[MR], bf[NR];                                                        \
      _Pragma("unroll") for (int m = 0; m < MR; ++m)                                \
        af[m] = *(const short8*)((const char*)(sAp) + (wm * RSM + m * 16 + lr) * 128 + coff); \
      _Pragma("unroll") for (int n = 0; n < NR; ++n)                                \
        bf[n] = *(const short8*)((const char*)(sBp) + (wn * RSN + n * 16 + lr) * 128 + coff); \
      _Pragma("unroll") for (int m = 0; m < MR; ++m)                                \
        _Pragma("unroll") for (int n = 0; n < NR; ++n)                              \
          acc[m][n] = __builtin_amdgcn_mfma_f32_16x16x32_bf16(af[m], bf[n], acc[m][n], 0, 0, 0); \
    }                                                                               \
  } while (0)

  // pipeline: stage(t+1) issued before waiting tile t; counted vmcnt(8)
  STAGE(0, A0, B0);
#pragma unroll 1
  for (int kt = 0; kt < 14; kt += 2) {
    STAGE((kt + 1) * 64, A1, B1);
    PIPE_WAIT8; PIPE_BAR;
    __builtin_amdgcn_s_setprio(1);
    COMPUTE(A0, B0);
    __builtin_amdgcn_s_setprio(0);
    PIPE_ENDBAR;
    STAGE((kt + 2) * 64, A0, B0);
    PIPE_WAIT8; PIPE_BAR;
    __builtin_amdgcn_s_setprio(1);
    COMPUTE(A1, B1);
    __builtin_amdgcn_s_setprio(0);
    PIPE_ENDBAR;
  }
  STAGE(15 * 64, A1, B1);
  PIPE_WAIT8; PIPE_BAR;
  __builtin_amdgcn_s_setprio(1);
  COMPUTE(A0, B0);
  __builtin_amdgcn_s_setprio(0);
  PIPE_ENDBAR;
  PIPE_WAIT0; PIPE_BAR;
  __builtin_amdgcn_s_setprio(1);
  COMPUTE(A1, B1);
  __builtin_amdgcn_s_setprio(0);

#undef STAGE
#undef COMPUTE

#pragma unroll
  for (int n = 0; n < NR; ++n) {
    const int gc = n0 + wn * RSN + n * 16 + lr;
    const float bv = bias[gc];
#pragma unroll
    for (int m = 0; m < MR; ++m) {
      const int gr0 = m0 + wm * RSM + m * 16 + lg * 4;
#pragma unroll
      for (int r = 0; r < 4; ++r) {
        const float val = acc[m][n][r] + bv;
        if (F32OUT) Of[(size_t)(gr0 + r) * DM + gc] = val;
        else        O[(size_t)(gr0 + r) * DM + gc] = f2b(val);
      }
    }
  }
}

// ---------------------------------------------------------------------------
// Sliding-window flash attention (unchanged this round).
// ---------------------------------------------------------------------------
__global__ __launch_bounds__(256) void attn(
    const unsigned short* __restrict__ Q,
    const unsigned short* __restrict__ Km,
    const unsigned short* __restrict__ Vm,
    unsigned short* __restrict__ AO)
{
  const int q0 = blockIdx.x * 64;
  const int h = blockIdx.y;
  const int t = threadIdx.x;
  const int lane = t & 63, w = t >> 6;
  const int lr = lane & 15, lg = lane >> 4;

  __shared__ __align__(16) short Vt[64 * 40];
  __shared__ __align__(16) short Pl[4 * 16 * 40];

  const int kb0 = (q0 >= WIN) ? (q0 - WIN) : 0;
  const int nch = (q0 + 64 - kb0) >> 5;

  short8 qf[2];
  {
    const unsigned short* qp = Q + (size_t)(q0 + w * 16 + lr) * DM + h * DH + lg * 8;
    qf[0] = *(const short8*)qp;
    qf[1] = *(const short8*)(qp + 32);
  }

  f32x4 o[4];
#pragma unroll
  for (int dt = 0; dt < 4; ++dt) o[dt] = (f32x4){0.f, 0.f, 0.f, 0.f};
  float mrow[4], lrow[4];
#pragma unroll
  for (int r = 0; r < 4; ++r) { mrow[r] = -1e30f; lrow[r] = 0.f; }

  const int vkey = t >> 3;
  const int vd0 = (t & 7) * 8;

  for (int ch = 0; ch < nch; ++ch) {
    const int kb = kb0 + ch * 32;
    __syncthreads();

    {
      short8 vv = *(const short8*)(Vm + (size_t)(kb + vkey) * DM + h * DH + vd0);
#pragma unroll
      for (int j = 0; j < 8; ++j) Vt[(vd0 + j) * 40 + vkey] = vv[j];
    }

    f32x4 s[2];
    s[0] = (f32x4){0.f, 0.f, 0.f, 0.f};
    s[1] = (f32x4){0.f, 0.f, 0.f, 0.f};
#pragma unroll
    for (int ct = 0; ct < 2; ++ct) {
      const unsigned short* kp = Km + (size_t)(kb + ct * 16 + lr) * DM + h * DH + lg * 8;
      short8 k0 = *(const short8*)kp;
      short8 k1 = *(const short8*)(kp + 32);
      s[ct] = __builtin_amdgcn_mfma_f32_16x16x32_bf16(qf[0], k0, s[ct], 0, 0, 0);
      s[ct] = __builtin_amdgcn_mfma_f32_16x16x32_bf16(qf[1], k1, s[ct], 0, 0, 0);
    }

    float sv[2][4], pm[4];
    const int qg0 = q0 + w * 16 + lg * 4;
#pragma unroll
    for (int r = 0; r < 4; ++r) {
#pragma unroll
      for (int ct = 0; ct < 2; ++ct) {
        const int key = kb + ct * 16 + lr;
        const int qr = qg0 + r;
        const bool valid = (key <= qr) && (qr - key < WIN);
        sv[ct][r] = valid ? s[ct][r] * 0.125f : -1e30f;
      }
      pm[r] = fmaxf(sv[0][r], sv[1][r]);
    }
#pragma unroll
    for (int off = 1; off < 16; off <<= 1)
#pragma unroll
      for (int r = 0; r < 4; ++r) pm[r] = fmaxf(pm[r], __shfl_xor(pm[r], off, 64));

    float fac[4], rs[4], p[2][4];
#pragma unroll
    for (int r = 0; r < 4; ++r) {
      const float mn = fmaxf(mrow[r], pm[r]);
      fac[r] = __expf(mrow[r] - mn);
      mrow[r] = mn;
      p[0][r] = (sv[0][r] < -1e29f) ? 0.f : __expf(sv[0][r] - mn);
      p[1][r] = (sv[1][r] < -1e29f) ? 0.f : __expf(sv[1][r] - mn);
      rs[r] = p[0][r] + p[1][r];
    }
#pragma unroll
    for (int off = 1; off < 16; off <<= 1)
#pragma unroll
      for (int r = 0; r < 4; ++r) rs[r] += __shfl_xor(rs[r], off, 64);
#pragma unroll
    for (int r = 0; r < 4; ++r) lrow[r] = lrow[r] * fac[r] + rs[r];
#pragma unroll
    for (int dt = 0; dt < 4; ++dt)
#pragma unroll
      for (int r = 0; r < 4; ++r) o[dt][r] *= fac[r];

#pragma unroll
    for (int r = 0; r < 4; ++r)
#pragma unroll
      for (int ct = 0; ct < 2; ++ct)
        Pl[(w * 16 + lg * 4 + r) * 40 + ct * 16 + lr] = (short)f2b(p[ct][r]);

    __syncthreads();

    short8 pa = *(const short8*)(Pl + (w * 16 + lr) * 40 + lg * 8);
#pragma unroll
    for (int dt = 0; dt < 4; ++dt) {
      short8 vb = *(const short8*)(Vt + (dt * 16 + lr) * 40 + lg * 8);
      o[dt] = __builtin_amdgcn_mfma_f32_16x16x32_bf16(pa, vb, o[dt], 0, 0, 0);
    }
  }

  float inv[4];
#pragma unroll
  for (int r = 0; r < 4; ++r) inv[r] = 1.f / lrow[r];
#pragma unroll
  for (int dt = 0; dt < 4; ++dt)
#pragma unroll
    for (int r = 0; r < 4; ++r)
      AO[(size_t)(q0 + w * 16 + lg * 4 + r) * DM + h * DH + dt * 16 + lr] =
          f2b(o[dt][r] * inv[r]);
}

// ---------------------------------------------------------------------------
extern "C" void kernel_launch(void* const* d_in, const int* in_sizes, int n_in,
                              void* d_out, int out_size, void* d_ws, size_t ws_size,
                              hipStream_t stream) {
  const float* x  = (const float*)d_in[0];
  const float* qw = (const float*)d_in[1];
  const float* qb = (const float*)d_in[2];
  const float* kw = (const float*)d_in[3];
  const float* kb = (const float*)d_in[4];
  const float* vw = (const float*)d_in[5];
  const float* vb = (const float*)d_in[6];
  const float* ow = (const float*)d_in[7];
  const float* ob = (const float*)d_in[8];

  const size_t SD = (size_t)S_LEN * DM;
  unsigned short* Qb  = (unsigned short*)d_ws;
  unsigned short* Kb  = Qb + SD;
  unsigned short* Vb  = Kb + SD;
  unsigned short* AOb = Vb + SD;
  unsigned short* Xb  = AOb + SD;
  unsigned short* Wcv = Xb + SD;

  cvt_all<<<dim3(2048, 5), 256, 0, stream>>>(x, qw, kw, vw, ow, Xb, Wcv);
  gemm_bt<256, 256, 2, 4, false><<<dim3(16, 4, 3), 512, 0, stream>>>(
      Xb, Wcv, qb, kb, vb, Qb, nullptr);
  attn<<<dim3(S_LEN / 64, NH), 256, 0, stream>>>(Qb, Kb, Vb, AOb);
  gemm_bt<128, 128, 2, 2, true><<<dim3(32, 8, 1), 256, 0, stream>>>(
      AOb, Wcv + (size_t)3 * DM * DM, ob, ob, ob, nullptr, (float*)d_out);
}

// Round 6
// 86.638 us; speedup vs baseline: 1.4839x; 1.1538x over previous
//
#include <hip/hip_runtime.h>

typedef __attribute__((ext_vector_type(4))) float f32x4;
typedef __attribute__((ext_vector_type(16))) float f32x16;
typedef __attribute__((ext_vector_type(8))) short short8;
typedef __attribute__((ext_vector_type(4))) int i32x4;

#define S_LEN 4096
#define DM    1024
#define NH    16
#define DH    64
#define WIN   256

__device__ inline unsigned short f2b(float f) {
  unsigned int x = __float_as_uint(f);
  unsigned int r = (x + 0x7fffu + ((x >> 16) & 1u)) >> 16;
  return (unsigned short)r;
}

__device__ inline void gload_lds16(const void* g, void* l) {
  __builtin_amdgcn_global_load_lds(
      (const __attribute__((address_space(1))) void*)g,
      (__attribute__((address_space(3))) void*)l, 16, 0, 0);
}

// ---------------------------------------------------------------------------
// Convert X and the 4 weight matrices f32 -> bf16.
// ---------------------------------------------------------------------------
__global__ __launch_bounds__(256) void cvt_all(
    const float* __restrict__ x,
    const float* __restrict__ qw, const float* __restrict__ kw,
    const float* __restrict__ vw, const float* __restrict__ ow,
    unsigned short* __restrict__ Xb, unsigned short* __restrict__ Wb)
{
  const int y = blockIdx.y;
  const float* src;
  unsigned short* dst;
  int n8;
  if (y == 0) { src = x; dst = Xb; n8 = (S_LEN * DM) / 8; }
  else {
    src = (y == 1) ? qw : (y == 2) ? kw : (y == 3) ? vw : ow;
    dst = Wb + (size_t)(y - 1) * DM * DM;
    n8 = (DM * DM) / 8;
  }
  const int i = blockIdx.x * 256 + threadIdx.x;
  if (i >= n8) return;
  const float4* s4 = (const float4*)src + (size_t)i * 2;
  float4 a = s4[0], b = s4[1];
  short8 v;
  v[0] = f2b(a.x); v[1] = f2b(a.y); v[2] = f2b(a.z); v[3] = f2b(a.w);
  v[4] = f2b(b.x); v[5] = f2b(b.y); v[6] = f2b(b.z); v[7] = f2b(b.w);
  *(short8*)(dst + (size_t)i * 8) = v;
}

// ---------------------------------------------------------------------------
// Deep-pipelined GEMM (unchanged): counted vmcnt, LDS swizzle, setprio.
// qkv: 256x256 tile, 8 waves.  out: 128x128 tile, 4 waves.
// ---------------------------------------------------------------------------
#define PIPE_WAIT8  asm volatile("s_waitcnt vmcnt(8)" ::: "memory")
#define PIPE_WAIT0  asm volatile("s_waitcnt vmcnt(0)" ::: "memory")
#define PIPE_BAR    do { __builtin_amdgcn_s_barrier(); __builtin_amdgcn_sched_barrier(0); } while (0)
#define PIPE_ENDBAR do { __builtin_amdgcn_sched_barrier(0); __builtin_amdgcn_s_barrier(); \
                         __builtin_amdgcn_sched_barrier(0); } while (0)

template<int BM, int BN, int NWM, int NWN, bool F32OUT>
__global__ __launch_bounds__(NWM* NWN * 64, 1) void gemm_bt(
    const unsigned short* __restrict__ A,
    const unsigned short* __restrict__ Wb,
    const float* __restrict__ b0, const float* __restrict__ b1, const float* __restrict__ b2,
    unsigned short* __restrict__ Obf,
    float* __restrict__ Of)
{
  constexpr int THREADS = NWM * NWN * 64;
  constexpr int MR = BM / (NWM * 16);
  constexpr int NR = BN / (NWN * 16);
  constexpr int RSM = BM / NWM;
  constexpr int RSN = BN / NWN;
  constexpr int REG = BM * 64;
  static_assert(BM == BN, "");
  static_assert((BM * 64 * 2) / (THREADS * 16) == 4, "4 staging rounds");

  const int z = blockIdx.z;
  const unsigned short* Bmat = Wb + (size_t)z * DM * DM;
  const float* bias = (z == 0) ? b0 : (z == 1) ? b1 : b2;
  unsigned short* O = Obf + (size_t)z * S_LEN * DM;

  __shared__ __align__(16) unsigned short LDS[4 * REG];
  unsigned short* A0 = LDS;
  unsigned short* A1 = LDS + REG;
  unsigned short* B0 = LDS + 2 * REG;
  unsigned short* B1 = LDS + 3 * REG;

  const int t = threadIdx.x;
  const int lane = t & 63, w = t >> 6;
  const int wm = w / NWN, wn = w % NWN;
  const int lr = lane & 15, lg = lane >> 4;
  const int m0 = blockIdx.x * BM, n0 = blockIdx.y * BN;

  int srow[4], scol[4], sbase[4];
#pragma unroll
  for (int i = 0; i < 4; ++i) {
    const int bo = (i * THREADS + w * 64) * 16;
    const int o = bo + lane * 16;
    const int row = o >> 7, colb = o & 127;
    const int colp = colb ^ ((row & 3) << 4) ^ (((row >> 2) & 1) << 6);
    srow[i] = row; scol[i] = colp >> 1; sbase[i] = bo >> 1;
  }

#define STAGE(e0, lA, lB)                                                           \
  do {                                                                              \
    _Pragma("unroll") for (int i = 0; i < 4; ++i) {                                 \
      gload_lds16(A + (size_t)(m0 + srow[i]) * DM + (e0) + scol[i], (lA) + sbase[i]); \
      gload_lds16(Bmat + (size_t)(n0 + srow[i]) * DM + (e0) + scol[i], (lB) + sbase[i]); \
    }                                                                               \
  } while (0)

  f32x4 acc[MR][NR];
#pragma unroll
  for (int m = 0; m < MR; ++m)
#pragma unroll
    for (int n = 0; n < NR; ++n) acc[m][n] = (f32x4){0.f, 0.f, 0.f, 0.f};

  const int xor6l = ((lr >> 2) & 1) << 6;
  const int xor45 = (lg << 4) ^ ((lr & 3) << 4);

#define COMPUTE(sAp, sBp)                                                           \
  do {                                                                              \
    _Pragma("unroll") for (int kk = 0; kk < 2; ++kk) {                              \
      const int coff = ((kk << 6) ^ xor6l) + xor45;                                 \
      short8 af[MR], bf[NR];                                                        \
      _Pragma("unroll") for (int m = 0; m < MR; ++m)                                \
        af[m] = *(const short8*)((const char*)(sAp) + (wm * RSM + m * 16 + lr) * 128 + coff); \
      _Pragma("unroll") for (int n = 0; n < NR; ++n)                                \
        bf[n] = *(const short8*)((const char*)(sBp) + (wn * RSN + n * 16 + lr) * 128 + coff); \
      _Pragma("unroll") for (int m = 0; m < MR; ++m)                                \
        _Pragma("unroll") for (int n = 0; n < NR; ++n)                              \
          acc[m][n] = __builtin_amdgcn_mfma_f32_16x16x32_bf16(af[m], bf[n], acc[m][n], 0, 0, 0); \
    }                                                                               \
  } while (0)

  STAGE(0, A0, B0);
#pragma unroll 1
  for (int kt = 0; kt < 14; kt += 2) {
    STAGE((kt + 1) * 64, A1, B1);
    PIPE_WAIT8; PIPE_BAR;
    __builtin_amdgcn_s_setprio(1);
    COMPUTE(A0, B0);
    __builtin_amdgcn_s_setprio(0);
    PIPE_ENDBAR;
    STAGE((kt + 2) * 64, A0, B0);
    PIPE_WAIT8; PIPE_BAR;
    __builtin_amdgcn_s_setprio(1);
    COMPUTE(A1, B1);
    __builtin_amdgcn_s_setprio(0);
    PIPE_ENDBAR;
  }
  STAGE(15 * 64, A1, B1);
  PIPE_WAIT8; PIPE_BAR;
  __builtin_amdgcn_s_setprio(1);
  COMPUTE(A0, B0);
  __builtin_amdgcn_s_setprio(0);
  PIPE_ENDBAR;
  PIPE_WAIT0; PIPE_BAR;
  __builtin_amdgcn_s_setprio(1);
  COMPUTE(A1, B1);
  __builtin_amdgcn_s_setprio(0);

#undef STAGE
#undef COMPUTE

#pragma unroll
  for (int n = 0; n < NR; ++n) {
    const int gc = n0 + wn * RSN + n * 16 + lr;
    const float bv = bias[gc];
#pragma unroll
    for (int m = 0; m < MR; ++m) {
      const int gr0 = m0 + wm * RSM + m * 16 + lg * 4;
#pragma unroll
      for (int r = 0; r < 4; ++r) {
        const float val = acc[m][n][r] + bv;
        if (F32OUT) Of[(size_t)(gr0 + r) * DM + gc] = val;
        else        O[(size_t)(gr0 + r) * DM + gc] = f2b(val);
      }
    }
  }
}

// ---------------------------------------------------------------------------
// Sliding-window attention v2 (fixed): 1 warp per 32 q-rows, 32x32x16 MFMA,
// swapped QK^T, static-max softmax, zero barriers, K/V prefetch.
// BUGFIX vs round 4: macro-local chunk base renamed kbv — previous
// `const int kb = (kb + 32);` self-initialized (UB) -> garbage mask ->
// lsum==0 -> 0*inf = NaN.
// ---------------------------------------------------------------------------
__global__ __launch_bounds__(256) void attn(
    const unsigned short* __restrict__ Q,
    const unsigned short* __restrict__ Km,
    const unsigned short* __restrict__ Vm,
    unsigned short* __restrict__ AO)
{
  const int warp = threadIdx.x >> 6;
  const int l = threadIdx.x & 63;
  const int qw0 = (blockIdx.x * 4 + warp) * 32;
  const int hD = blockIdx.y * DH;
  const int q = l & 31;
  const int hi = l >> 5;
  const int l31 = l & 31;
  const int vkey = (l & 15) * 2;
  const int vd0 = (l >> 4) * 16;

  __shared__ __align__(16) unsigned short VtS[4][2][64 * 40];
  unsigned short* vt0 = &VtS[warp][0][0];
  unsigned short* vt1 = &VtS[warp][1][0];

  short8 qf[4];
  {
    const unsigned short* qp = Q + (size_t)(qw0 + q) * DM + hD + hi * 8;
#pragma unroll
    for (int ks = 0; ks < 4; ++ks) qf[ks] = *(const short8*)(qp + ks * 16);
  }

  f32x16 o0{}, o1{};
  float lsum = 0.f;

  const int kb0 = (qw0 >= WIN) ? (qw0 - WIN) : 0;
  const int nch = (qw0 + 32 - kb0) >> 5;

  short8 kfA[4], vfA[4], kfB[4], vfB[4];

#define LOADKV(kb_, kf_, vf_)                                                    \
  do {                                                                           \
    const unsigned short* kp_ = Km + (size_t)((kb_) + l31) * DM + hD + hi * 8;   \
    (kf_)[0] = *(const short8*)kp_;                                              \
    (kf_)[1] = *(const short8*)(kp_ + 16);                                       \
    (kf_)[2] = *(const short8*)(kp_ + 32);                                       \
    (kf_)[3] = *(const short8*)(kp_ + 48);                                       \
    const unsigned short* vp_ = Vm + (size_t)((kb_) + vkey) * DM + hD + vd0;     \
    (vf_)[0] = *(const short8*)vp_;                                              \
    (vf_)[1] = *(const short8*)(vp_ + 8);                                        \
    (vf_)[2] = *(const short8*)(vp_ + DM);                                       \
    (vf_)[3] = *(const short8*)(vp_ + DM + 8);                                   \
  } while (0)

#define PROCESS(kb_, kf_, vf_, vt_)                                             \
  do {                                                                          \
    const int kbv = (kb_);                                                      \
    _Pragma("unroll") for (int j = 0; j < 16; ++j) {                            \
      unsigned int wv = (unsigned int)(unsigned short)(vf_)[j >> 3][j & 7]      \
          | ((unsigned int)(unsigned short)(vf_)[2 + (j >> 3)][j & 7] << 16);   \
      *(unsigned int*)((vt_) + (vd0 + j) * 40 + vkey) = wv;                     \
    }                                                                           \
    f32x16 s{};                                                                 \
    _Pragma("unroll") for (int ks = 0; ks < 4; ++ks)                            \
      s = __builtin_amdgcn_mfma_f32_32x32x16_bf16((kf_)[ks], qf[ks], s, 0, 0, 0); \
    float p[16];                                                                \
    const bool isEdge = (kbv >= qw0) || (kbv + WIN - 32 < qw0);                 \
    if (isEdge) {                                                               \
      _Pragma("unroll") for (int r = 0; r < 16; ++r) {                          \
        const int key = kbv + (r & 3) + 8 * (r >> 2) + 4 * hi;                  \
        const int qg = qw0 + q;                                                 \
        const bool valid = (key <= qg) && (qg - key < WIN);                     \
        p[r] = __expf(valid ? s[r] * 0.125f : -1e30f);                          \
        lsum += p[r];                                                           \
      }                                                                         \
    } else {                                                                    \
      _Pragma("unroll") for (int r = 0; r < 16; ++r) {                          \
        p[r] = __expf(s[r] * 0.125f);                                           \
        lsum += p[r];                                                           \
      }                                                                         \
    }                                                                           \
    unsigned int u[8];                                                          \
    _Pragma("unroll") for (int t2 = 0; t2 < 4; ++t2) {                          \
      u[2 * t2]     = (unsigned int)f2b(p[4 * t2])     | ((unsigned int)f2b(p[4 * t2 + 1]) << 16); \
      u[2 * t2 + 1] = (unsigned int)f2b(p[4 * t2 + 2]) | ((unsigned int)f2b(p[4 * t2 + 3]) << 16); \
    }                                                                           \
    const unsigned int sd0 = hi ? u[0] : u[2], sd1 = hi ? u[1] : u[3];          \
    const unsigned int rc0 = __shfl_xor(sd0, 32, 64), rc1 = __shfl_xor(sd1, 32, 64); \
    const unsigned int sd2 = hi ? u[4] : u[6], sd3 = hi ? u[5] : u[7];          \
    const unsigned int rc2 = __shfl_xor(sd2, 32, 64), rc3 = __shfl_xor(sd3, 32, 64); \
    i32x4 pw0, pw1;                                                             \
    pw0[0] = hi ? rc0 : u[0]; pw0[1] = hi ? rc1 : u[1];                         \
    pw0[2] = hi ? u[2] : rc0; pw0[3] = hi ? u[3] : rc1;                         \
    pw1[0] = hi ? rc2 : u[4]; pw1[1] = hi ? rc3 : u[5];                         \
    pw1[2] = hi ? u[6] : rc2; pw1[3] = hi ? u[7] : rc3;                         \
    const short8 pf0 = *(const short8*)&pw0;                                    \
    const short8 pf1 = *(const short8*)&pw1;                                    \
    const short8 a00 = *(const short8*)((vt_) + l31 * 40 + hi * 8);             \
    const short8 a01 = *(const short8*)((vt_) + l31 * 40 + 16 + hi * 8);        \
    const short8 a10 = *(const short8*)((vt_) + (32 + l31) * 40 + hi * 8);      \
    const short8 a11 = *(const short8*)((vt_) + (32 + l31) * 40 + 16 + hi * 8); \
    o0 = __builtin_amdgcn_mfma_f32_32x32x16_bf16(a00, pf0, o0, 0, 0, 0);        \
    o0 = __builtin_amdgcn_mfma_f32_32x32x16_bf16(a01, pf1, o0, 0, 0, 0);        \
    o1 = __builtin_amdgcn_mfma_f32_32x32x16_bf16(a10, pf0, o1, 0, 0, 0);        \
    o1 = __builtin_amdgcn_mfma_f32_32x32x16_bf16(a11, pf1, o1, 0, 0, 0);        \
  } while (0)

  LOADKV(kb0, kfA, vfA);
  int c = 0;
#pragma unroll 1
  for (; c + 2 <= nch; c += 2) {
    const int kb = kb0 + c * 32;
    LOADKV(kb + 32, kfB, vfB);
    PROCESS(kb, kfA, vfA, vt0);
    if (c + 2 < nch) LOADKV(kb + 64, kfA, vfA);
    PROCESS(kb + 32, kfB, vfB, vt1);
  }
  if (c < nch) PROCESS(kb0 + c * 32, kfA, vfA, vt0);

#undef LOADKV
#undef PROCESS

  lsum += __shfl_xor(lsum, 32, 64);
  const float inv = 1.f / lsum;
  unsigned short* aop = AO + (size_t)(qw0 + q) * DM + hD;
#pragma unroll
  for (int t2 = 0; t2 < 4; ++t2) {
    uint2 st;
    st.x = (unsigned int)f2b(o0[4 * t2] * inv)     | ((unsigned int)f2b(o0[4 * t2 + 1] * inv) << 16);
    st.y = (unsigned int)f2b(o0[4 * t2 + 2] * inv) | ((unsigned int)f2b(o0[4 * t2 + 3] * inv) << 16);
    *(uint2*)(aop + 8 * t2 + 4 * hi) = st;
    uint2 st2;
    st2.x = (unsigned int)f2b(o1[4 * t2] * inv)     | ((unsigned int)f2b(o1[4 * t2 + 1] * inv) << 16);
    st2.y = (unsigned int)f2b(o1[4 * t2 + 2] * inv) | ((unsigned int)f2b(o1[4 * t2 + 3] * inv) << 16);
    *(uint2*)(aop + 32 + 8 * t2 + 4 * hi) = st2;
  }
}

// ---------------------------------------------------------------------------
extern "C" void kernel_launch(void* const* d_in, const int* in_sizes, int n_in,
                              void* d_out, int out_size, void* d_ws, size_t ws_size,
                              hipStream_t stream) {
  const float* x  = (const float*)d_in[0];
  const float* qw = (const float*)d_in[1];
  const float* qb = (const float*)d_in[2];
  const float* kw = (const float*)d_in[3];
  const float* kb = (const float*)d_in[4];
  const float* vw = (const float*)d_in[5];
  const float* vb = (const float*)d_in[6];
  const float* ow = (const float*)d_in[7];
  const float* ob = (const float*)d_in[8];

  const size_t SD = (size_t)S_LEN * DM;
  unsigned short* Qb  = (unsigned short*)d_ws;
  unsigned short* Kb  = Qb + SD;
  unsigned short* Vb  = Kb + SD;
  unsigned short* AOb = Vb + SD;
  unsigned short* Xb  = AOb + SD;
  unsigned short* Wcv = Xb + SD;

  cvt_all<<<dim3(2048, 5), 256, 0, stream>>>(x, qw, kw, vw, ow, Xb, Wcv);
  gemm_bt<256, 256, 2, 4, false><<<dim3(16, 4, 3), 512, 0, stream>>>(
      Xb, Wcv, qb, kb, vb, Qb, nullptr);
  attn<<<dim3(S_LEN / 128, NH), 256, 0, stream>>>(Qb, Kb, Vb, AOb);
  gemm_bt<128, 128, 2, 2, true><<<dim3(32, 8, 1), 256, 0, stream>>>(
      AOb, Wcv + (size_t)3 * DM * DM, ob, ob, ob, nullptr, (float*)d_out);
}